// Round 8
// baseline (158.684 us; speedup 1.0000x reference)
//
#include <hip/hip_runtime.h>
#include <stdint.h>

typedef float f32x4 __attribute__((ext_vector_type(4)));
typedef _Float16 f16;
typedef f16 f16x8 __attribute__((ext_vector_type(8)));
typedef f16 f16x4 __attribute__((ext_vector_type(4)));

#define MFMA16(a, b, c) __builtin_amdgcn_mfma_f32_16x16x32_f16((a), (b), (c), 0, 0, 0)

typedef __attribute__((address_space(1))) const uint32_t gu32;
typedef __attribute__((address_space(3))) uint32_t lu32;
__device__ __forceinline__ void gload_lds16(const void* g, void* l) {
    __builtin_amdgcn_global_load_lds((gu32*)g, (lu32*)l, 16, 0, 0);
}

// K tile image: per (head bh, kv-tile kt) a contiguous 4096-elem (8 KB)
// buffer; elem (row, k) at  row*64 + (((k>>3) ^ (row&7)) << 3) + (k&7).
__device__ __forceinline__ size_t kv_elem(int bh, int n, int d) {
    const int kt = n >> 6, row = n & 63;
    return ((size_t)(bh * 32 + kt)) * 4096 + row * 64 + (((d >> 3) ^ (row & 7)) << 3) + (d & 7);
}

// ---------------------------------------------------------------------------
// Kernel 1: convert fp32 inputs to fp16 (X split hi/lo; w_qkv rows permuted).
// ---------------------------------------------------------------------------
__global__ void split_inputs(const float* __restrict__ X, const float* __restrict__ Wq,
                             const float* __restrict__ Wf,
                             f16* __restrict__ Xh, f16* __restrict__ Xl,
                             f16* __restrict__ Wh, f16* __restrict__ Wfb) {
    const int tid = blockIdx.x * 256 + threadIdx.x;
    if (tid < 393216) {                       // X: 3,145,728 floats
        const float* s = X + (size_t)tid * 8;
        f16 hi[8], lo[8];
#pragma unroll
        for (int j = 0; j < 8; j += 4) {
            f32x4 v = *(const f32x4*)(s + j);
#pragma unroll
            for (int q = 0; q < 4; ++q) {
                f16 h = (f16)v[q];
                hi[j + q] = h;
                lo[j + q] = (f16)(v[q] - (float)h);
            }
        }
        *(f16x8*)(Xh + (size_t)tid * 8) = *(f16x8*)hi;
        *(f16x8*)(Xl + (size_t)tid * 8) = *(f16x8*)lo;
    } else if (tid < 614400) {                // w_qkv: row c*768+d*12+h -> c*768+h*64+d
        const int t2 = tid - 393216;
        const int row = t2 / 96;
        const int k = (t2 % 96) * 8;
        const int c = row / 768;
        const int rem = row - c * 768;
        const int d = rem / 12;
        const int h2 = rem - d * 12;
        const int cp = c * 768 + h2 * 64 + d;
        const float* s = Wq + (size_t)row * 768 + k;
        f16 hi[8];
#pragma unroll
        for (int j = 0; j < 8; j += 4) {
            f32x4 v = *(const f32x4*)(s + j);
#pragma unroll
            for (int q = 0; q < 4; ++q) hi[j + q] = (f16)v[q];
        }
        *(f16x8*)(Wh + (size_t)cp * 768 + k) = *(f16x8*)hi;
    } else {                                  // w_fc
        const int t2 = tid - 614400;
        const float* s = Wf + (size_t)t2 * 8;
        f16 hi[8];
#pragma unroll
        for (int j = 0; j < 8; j += 4) {
            f32x4 v = *(const f32x4*)(s + j);
#pragma unroll
            for (int q = 0; q < 4; ++q) hi[j + q] = (f16)v[q];
        }
        *(f16x8*)(Wfb + (size_t)t2 * 8) = *(f16x8*)hi;
    }
}

// ---------------------------------------------------------------------------
// Kernel 2: qkv GEMM (R5/R7 verbatim). fp16, Q/K cols 2 MFMA (x hi+lo), V 1.
// ---------------------------------------------------------------------------
__global__ __launch_bounds__(256) void qkv_gemm(
    const f16* __restrict__ Xh, const f16* __restrict__ Xl,
    const f16* __restrict__ Wh,
    f16* __restrict__ Qh, f16* __restrict__ Ql,
    f16* __restrict__ Khg, f16* __restrict__ Vb) {
    __shared__ f16 Ah[128 * 32], Al[128 * 32], Bh[128 * 32];
    const int t = threadIdx.x;
    const int lane = t & 63, wv = t >> 6;
    const int wm = (wv >> 1) * 64, wn = (wv & 1) * 64;
    const int r = lane & 15, g = lane >> 4;
    const int bm = blockIdx.x, bn = blockIdx.y;
    const bool full = (bn < 12);   // Q/K need the x-lo pass; V doesn't

    const int lrow = lane >> 2;
    const int lk = (lane & 3) * 8;

    f32x4 acc[4][4];
#pragma unroll
    for (int i = 0; i < 4; ++i)
#pragma unroll
        for (int j = 0; j < 4; ++j) acc[i][j] = (f32x4)0.0f;

    for (int ks = 0; ks < 768; ks += 32) {
#pragma unroll
        for (int hh = 0; hh < 2; ++hh) {
            const int ii = wv * 2 + hh;
            const int grow = ii * 16 + lrow;
            const size_t ga = (size_t)(bm * 128 + grow) * 768 + ks + lk;
            const size_t gb = (size_t)(bn * 128 + grow) * 768 + ks + lk;
            const int lbase = ii * 512;                  // wave-uniform LDS base
            gload_lds16(Xh + ga, &Ah[lbase]);
            gload_lds16(Wh + gb, &Bh[lbase]);
            if (full) gload_lds16(Xl + ga, &Al[lbase]);
        }
        __syncthreads();

        f16x8 a_h[4], b[4];
#pragma unroll
        for (int mf = 0; mf < 4; ++mf) a_h[mf] = *(f16x8*)&Ah[(wm + mf * 16 + r) * 32 + g * 8];
#pragma unroll
        for (int nf = 0; nf < 4; ++nf) b[nf] = *(f16x8*)&Bh[(wn + nf * 16 + r) * 32 + g * 8];
        if (full) {
            f16x8 a_l[4];
#pragma unroll
            for (int mf = 0; mf < 4; ++mf) a_l[mf] = *(f16x8*)&Al[(wm + mf * 16 + r) * 32 + g * 8];
#pragma unroll
            for (int mf = 0; mf < 4; ++mf)
#pragma unroll
                for (int nf = 0; nf < 4; ++nf) {
                    acc[mf][nf] = MFMA16(a_h[mf], b[nf], acc[mf][nf]);
                    acc[mf][nf] = MFMA16(a_l[mf], b[nf], acc[mf][nf]);
                }
        } else {
#pragma unroll
            for (int mf = 0; mf < 4; ++mf)
#pragma unroll
                for (int nf = 0; nf < 4; ++nf)
                    acc[mf][nf] = MFMA16(a_h[mf], b[nf], acc[mf][nf]);
        }
        __syncthreads();
    }

    const int comp = bn / 6;
#pragma unroll
    for (int mf = 0; mf < 4; ++mf)
#pragma unroll
        for (int nf = 0; nf < 4; ++nf) {
            const int col = bn * 128 + wn + nf * 16 + r;
            const int h = (col >> 6) % 12;
            const int d = col & 63;
#pragma unroll
            for (int v = 0; v < 4; ++v) {
                const int row = bm * 128 + wm + mf * 16 + g * 4 + v;
                const int b2 = row >> 11, n = row & 2047;
                const int bh = b2 * 12 + h;
                float val = acc[mf][nf][v];
                if (comp == 0) {
                    const size_t dest = ((size_t)bh * 2048 + n) * 64 + d;
                    val *= 8.0f;  // fold temperature (reference MULTIPLIES by sqrt(d_k))
                    f16 hi = (f16)val;
                    Qh[dest] = hi;
                    Ql[dest] = (f16)(val - (float)hi);
                } else if (comp == 1) {
                    Khg[kv_elem(bh, n, d)] = (f16)val;
                } else {
                    Vb[((size_t)bh * 2048 + n) * 64 + d] = (f16)val;
                }
            }
        }
}

// ---------------------------------------------------------------------------
// Kernel 2b: V transpose into the PERMUTED tiled image.
// Element (kv_local = kv&63, d) of tile (bh,kt) stored at f16 index
//   kc*2048 + d*32 + (g ^ ((d>>1)&3))*8 + u*4 + v
// where kv_local = kc*32 + u*16 + g*4 + v.  A b128 read at
// [kc*2048 + d*32 + (g^((d>>1)&3))*8] yields exactly lane (r,g)'s 8 PV
// k-slots {kc*32+g*4+0..3, kc*32+16+g*4+0..3}. grid 768, block 256.
// ---------------------------------------------------------------------------
__global__ void v_transpose(const f16* __restrict__ Vb, f16* __restrict__ VTg) {
    __shared__ f16 Vt[64 * 72];
    const int t = threadIdx.x;
    const int tile = blockIdx.x;              // bh*32 + kt
    const f16* src = Vb + (size_t)tile * 4096;
    const int row = t >> 2, d0 = (t & 3) * 16;
    *(f16x8*)&Vt[row * 72 + d0]     = *(const f16x8*)(src + row * 64 + d0);
    *(f16x8*)&Vt[row * 72 + d0 + 8] = *(const f16x8*)(src + row * 64 + d0 + 8);
    __syncthreads();
    f16* dst = VTg + (size_t)tile * 4096;
#pragma unroll
    for (int it = 0; it < 2; ++it) {
        const int c = t + it * 256;           // chunk id 0..511
        const int kc = c >> 8;
        const int d = (c >> 2) & 63;
        const int gg = c & 3;
        const int gl = gg ^ ((d >> 1) & 3);   // logical reader group g
        f16 o[8];
#pragma unroll
        for (int j = 0; j < 8; ++j) {
            const int kv = kc * 32 + (j >> 2) * 16 + gl * 4 + (j & 3);
            o[j] = Vt[kv * 72 + d];
        }
        *(f16x8*)(dst + (size_t)c * 8) = *(f16x8*)o;
    }
}

// ---------------------------------------------------------------------------
// Kernel 3: flash attention PARTIAL (KV-split x3). 2 q-fragments per wave
// (32 q rows), P kept fully IN REGISTERS (permuted-k PV), no P LDS traffic.
// Block = 4 waves = 128 q rows; grid 24*16*3 = 1152. LDS 16 KB.
// ---------------------------------------------------------------------------
__global__ __launch_bounds__(256, 4) void attn_partial(
    const f16* __restrict__ Qh, const f16* __restrict__ Ql,
    const f16* __restrict__ Khg, const f16* __restrict__ VTg,
    f16* __restrict__ OP, float* __restrict__ Mst, float* __restrict__ Lst) {
    __shared__ f16 Khs[4096], VTs[4096];

    const int t = threadIdx.x;
    const int lane = t & 63, wv = t >> 6;
    const int r = lane & 15, g = lane >> 4;
    const int bid = blockIdx.x;
    const int part = bid % 3;
    const int qb = (bid / 3) & 15;
    const int bh = bid / 48;          // 0..23
    const size_t headoff = (size_t)bh * 2048 * 64;
    const int q0w = qb * 128 + wv * 32;
    const int kt0 = part * 11;
    const int kt1 = (part == 2) ? 32 : kt0 + 11;

    // Q fragments (B-operand): lane (r,g), qf: Q[q0w+qf*16+r][kc*32+g*8..+7]
    f16x8 qh[2][2], ql[2][2];
#pragma unroll
    for (int qf = 0; qf < 2; ++qf)
#pragma unroll
        for (int kc = 0; kc < 2; ++kc) {
            const size_t off = headoff + (size_t)(q0w + qf * 16 + r) * 64 + kc * 32 + g * 8;
            qh[qf][kc] = *(const f16x8*)(Qh + off);
            ql[qf][kc] = *(const f16x8*)(Ql + off);
        }

    f32x4 o_acc[2][4];
    float m_run[2] = {-1e30f, -1e30f}, l_run[2] = {0.0f, 0.0f};
#pragma unroll
    for (int qf = 0; qf < 2; ++qf)
#pragma unroll
        for (int df = 0; df < 4; ++df) o_acc[qf][df] = (f32x4)0.0f;

    for (int kt = kt0; kt < kt1; ++kt) {
        // ---- stage K and permuted-V^T images (8 KB each)
        const size_t tb = ((size_t)bh * 32 + kt) * 4096;
#pragma unroll
        for (int c2 = 0; c2 < 2; ++c2) {
            const int c = wv * 2 + c2;
            const int go = c * 512 + lane * 8;
            gload_lds16(Khg + tb + go, &Khs[c * 512]);
            gload_lds16(VTg + tb + go, &VTs[c * 512]);
        }
        __syncthreads();

        // ---- S^T = K Q^T : lane (r,g), qf gets S[q][k=cf*16+g*4+v]
        f32x4 s[2][4];
#pragma unroll
        for (int qf = 0; qf < 2; ++qf)
#pragma unroll
            for (int cf = 0; cf < 4; ++cf) s[qf][cf] = (f32x4)0.0f;
#pragma unroll
        for (int kc = 0; kc < 2; ++kc) {
            f16x8 ka[4];
#pragma unroll
            for (int cf = 0; cf < 4; ++cf)
                ka[cf] = *(f16x8*)&Khs[(cf * 16 + r) * 64 + (((kc * 4 + g) ^ (r & 7)) << 3)];
#pragma unroll
            for (int cf = 0; cf < 4; ++cf)
#pragma unroll
                for (int qf = 0; qf < 2; ++qf) {
                    s[qf][cf] = MFMA16(ka[cf], qh[qf][kc], s[qf][cf]);
                    s[qf][cf] = MFMA16(ka[cf], ql[qf][kc], s[qf][cf]);
                }
        }

        // ---- online softmax (lane owns rows q0w+qf*16+r); P packed to regs
        f16x8 pa[2][2];
        float sc[2];
#pragma unroll
        for (int qf = 0; qf < 2; ++qf) {
            float mx = -1e30f;
#pragma unroll
            for (int cf = 0; cf < 4; ++cf)
#pragma unroll
                for (int v = 0; v < 4; ++v) mx = fmaxf(mx, s[qf][cf][v]);
            mx = fmaxf(mx, __shfl_xor(mx, 16));
            mx = fmaxf(mx, __shfl_xor(mx, 32));
            const float mn = fmaxf(m_run[qf], mx);
            sc[qf] = __expf(m_run[qf] - mn);
            m_run[qf] = mn;
            float rs = 0.0f;
#pragma unroll
            for (int cf = 0; cf < 4; ++cf)
#pragma unroll
                for (int v = 0; v < 4; ++v) {
                    const float p = __expf(s[qf][cf][v] - mn);
                    rs += p;
                    pa[qf][cf >> 1][(cf & 1) * 4 + v] = (f16)p;
                }
            rs += __shfl_xor(rs, 16);
            rs += __shfl_xor(rs, 32);
            l_run[qf] = l_run[qf] * sc[qf] + rs;
        }
        // rescale o_acc: row of o_acc[qf][.][v] is q = qf*16 + g*4+v
#pragma unroll
        for (int qf = 0; qf < 2; ++qf)
#pragma unroll
            for (int v = 0; v < 4; ++v) {
                const float scv = __shfl(sc[qf], g * 4 + v);
#pragma unroll
                for (int df = 0; df < 4; ++df) o_acc[qf][df][v] *= scv;
            }

        // ---- O += P @ V  (P from registers; V in matching permuted k-order)
#pragma unroll
        for (int kc = 0; kc < 2; ++kc)
#pragma unroll
            for (int df = 0; df < 4; ++df) {
                f16x8 vb = *(f16x8*)&VTs[kc * 2048 + (df * 16 + r) * 32 +
                                         ((g ^ ((r >> 1) & 3)) << 3)];
#pragma unroll
                for (int qf = 0; qf < 2; ++qf)
                    o_acc[qf][df] = MFMA16(pa[qf][kc], vb, o_acc[qf][df]);
            }
        __syncthreads();
    }

    // ---- write partial: unnormalized O (fp16) + m,l stats
    const int pb = bh * 3 + part;
#pragma unroll
    for (int qf = 0; qf < 2; ++qf) {
        if (g == 0) {
            Mst[pb * 2048 + q0w + qf * 16 + r] = m_run[qf];
            Lst[pb * 2048 + q0w + qf * 16 + r] = l_run[qf];
        }
#pragma unroll
        for (int df = 0; df < 4; ++df)
#pragma unroll
            for (int v = 0; v < 4; ++v) {
                const int n = q0w + qf * 16 + g * 4 + v;
                OP[((size_t)pb * 2048 + n) * 64 + df * 16 + r] = (f16)o_acc[qf][df][v];
            }
    }
}

// ---------------------------------------------------------------------------
// Kernel 3b: combine the three KV-parts -> AO [b, n, h*64+d] fp16.
// 786432 threads (4 d-elems each), grid 3072.
// ---------------------------------------------------------------------------
__global__ void attn_combine(const f16* __restrict__ OP, const float* __restrict__ Mst,
                             const float* __restrict__ Lst, f16* __restrict__ AO) {
    const int tid = blockIdx.x * 256 + threadIdx.x;
    const int d4 = (tid & 15) * 4;
    const int pr = tid >> 4;          // bh*2048 + n
    const int bh = pr >> 11, n = pr & 2047;
    const int i0 = (bh * 3) * 2048 + n;
    const float m0 = Mst[i0], m1 = Mst[i0 + 2048], m2 = Mst[i0 + 4096];
    const float m = fmaxf(fmaxf(m0, m1), m2);
    const float w0 = __expf(m0 - m), w1 = __expf(m1 - m), w2 = __expf(m2 - m);
    const float inv = 1.0f / (w0 * Lst[i0] + w1 * Lst[i0 + 2048] + w2 * Lst[i0 + 4096]);
    f16x4 o0 = *(const f16x4*)(OP + (size_t)i0 * 64 + d4);
    f16x4 o1 = *(const f16x4*)(OP + (size_t)(i0 + 2048) * 64 + d4);
    f16x4 o2 = *(const f16x4*)(OP + (size_t)(i0 + 4096) * 64 + d4);
    const int b = bh / 12, h = bh - b * 12;
    f16 out[4];
#pragma unroll
    for (int j = 0; j < 4; ++j)
        out[j] = (f16)((w0 * (float)o0[j] + w1 * (float)o1[j] + w2 * (float)o2[j]) * inv);
    *(f16x4*)(AO + ((size_t)(b * 2048 + n)) * 768 + h * 64 + d4) = *(f16x4*)out;
}

// ---------------------------------------------------------------------------
// Kernel 4: out = AO @ Wfb^T + b_fc. 64x64 tiles, XOR-swizzled LDS,
// grid (64, 12) = 768 blocks. (R7 verbatim)
// ---------------------------------------------------------------------------
__global__ __launch_bounds__(256) void fc_gemm(const f16* __restrict__ A,
                                               const f16* __restrict__ Wfb,
                                               const float* __restrict__ bias,
                                               float* __restrict__ OUT) {
    __shared__ f16 As[64 * 64], Bs[64 * 64];
    const int t = threadIdx.x;
    const int lane = t & 63, wv = t >> 6;
    const int wm = (wv >> 1) * 32, wn = (wv & 1) * 32;
    const int r = lane & 15, g = lane >> 4;
    const int bm = blockIdx.x, bn = blockIdx.y;

    f32x4 acc[2][2];
#pragma unroll
    for (int i = 0; i < 2; ++i)
#pragma unroll
        for (int j = 0; j < 2; ++j) acc[i][j] = (f32x4)0.0f;

    const int srow = t >> 2;
    const int ssg = (t & 3) * 2;

    for (int ks = 0; ks < 768; ks += 64) {
        const f16* as = A + (size_t)(bm * 64 + srow) * 768 + ks;
        const f16* bs = Wfb + (size_t)(bn * 64 + srow) * 768 + ks;
#pragma unroll
        for (int u = 0; u < 2; ++u) {
            const int sg = ssg + u;
            const int dst = srow * 64 + ((sg ^ (srow & 7)) << 3);
            *(f16x8*)&As[dst] = *(const f16x8*)(as + sg * 8);
            *(f16x8*)&Bs[dst] = *(const f16x8*)(bs + sg * 8);
        }
        __syncthreads();

#pragma unroll
        for (int kc = 0; kc < 2; ++kc) {
            f16x8 a[2], b[2];
#pragma unroll
            for (int mf = 0; mf < 2; ++mf) {
                const int row = wm + mf * 16 + r;
                a[mf] = *(f16x8*)&As[row * 64 + (((kc * 4 + g) ^ (row & 7)) << 3)];
            }
#pragma unroll
            for (int nf = 0; nf < 2; ++nf) {
                const int row = wn + nf * 16 + r;
                b[nf] = *(f16x8*)&Bs[row * 64 + (((kc * 4 + g) ^ (row & 7)) << 3)];
            }
#pragma unroll
            for (int mf = 0; mf < 2; ++mf)
#pragma unroll
                for (int nf = 0; nf < 2; ++nf)
                    acc[mf][nf] = MFMA16(a[mf], b[nf], acc[mf][nf]);
        }
        __syncthreads();
    }

#pragma unroll
    for (int nf = 0; nf < 2; ++nf) {
        const int col = bn * 64 + wn + nf * 16 + r;
        const float bv = bias[col];
#pragma unroll
        for (int mf = 0; mf < 2; ++mf) {
            const int row = bm * 64 + wm + mf * 16 + g * 4;
#pragma unroll
            for (int v = 0; v < 4; ++v)
                OUT[(size_t)(row + v) * 768 + col] = acc[mf][nf][v] + bv;
        }
    }
}

// ---------------------------------------------------------------------------
extern "C" void kernel_launch(void* const* d_in, const int* in_sizes, int n_in,
                              void* d_out, int out_size, void* d_ws, size_t ws_size,
                              hipStream_t stream) {
    (void)in_sizes; (void)n_in; (void)out_size; (void)ws_size;
    const float* x     = (const float*)d_in[0];   // [2,2048,768]
    const float* w_qkv = (const float*)d_in[1];   // [2304,768]
    const float* w_fc  = (const float*)d_in[2];   // [768,768]
    const float* b_fc  = (const float*)d_in[3];   // [768]
    float* out = (float*)d_out;                   // [2,2048,768] fp32

    char* ws = (char*)d_ws;
    // Zone dead after prologue (OP aliases it exactly: 72*2048*64 f16 = 3 * 3145728):
    f16* Xh  = (f16*)ws;                         // 3,145,728 f16 each
    f16* Xl  = Xh + 3145728;
    f16* Vb  = Xl + 3145728;                     // linear V, dead after v_transpose
    // Live through attn:
    f16* Qh  = Vb + 3145728;
    f16* Ql  = Qh + 3145728;
    f16* Khg = Ql + 3145728;
    f16* VTg = Khg + 3145728;
    f16* AO  = VTg + 3145728;
    f16* Wh  = AO + 3145728;                     // 1,769,472 f16
    f16* Wfb = Wh + 1769472;                     // 589,824 f16
    float* Mst = (float*)(Wfb + 589824);         // 147,456 floats (72 x 2048)
    float* Lst = Mst + 147456;
    f16* OP = Xh;                                // aliases [Xh|Xl|Vb], exact fit
    // total = 56,033,280 B

    split_inputs<<<2688, 256, 0, stream>>>(x, w_qkv, w_fc, Xh, Xl, Wh, Wfb);
    qkv_gemm<<<dim3(32, 18), 256, 0, stream>>>(Xh, Xl, Wh, Qh, Ql, Khg, Vb);
    v_transpose<<<768, 256, 0, stream>>>(Vb, VTg);
    attn_partial<<<1152, 256, 0, stream>>>(Qh, Ql, Khg, VTg, OP, Mst, Lst);
    attn_combine<<<3072, 256, 0, stream>>>(OP, Mst, Lst, AO);
    fc_gemm<<<dim3(64, 12), 256, 0, stream>>>(AO, Wfb, b_fc, out);
}

// Round 9
// 145.332 us; speedup vs baseline: 1.0919x; 1.0919x over previous
//
#include <hip/hip_runtime.h>
#include <stdint.h>

typedef float f32x4 __attribute__((ext_vector_type(4)));
typedef _Float16 f16;
typedef f16 f16x8 __attribute__((ext_vector_type(8)));
typedef f16 f16x4 __attribute__((ext_vector_type(4)));

#define MFMA16(a, b, c) __builtin_amdgcn_mfma_f32_16x16x32_f16((a), (b), (c), 0, 0, 0)

typedef __attribute__((address_space(1))) const uint32_t gu32;
typedef __attribute__((address_space(3))) uint32_t lu32;
__device__ __forceinline__ void gload_lds16(const void* g, void* l) {
    __builtin_amdgcn_global_load_lds((gu32*)g, (lu32*)l, 16, 0, 0);
}

// K tile image: per (head bh, kv-tile kt) a contiguous 4096-elem (8 KB)
// buffer; elem (row, k) at  row*64 + (((k>>3) ^ (row&7)) << 3) + (k&7).
__device__ __forceinline__ size_t kv_elem(int bh, int n, int d) {
    const int kt = n >> 6, row = n & 63;
    return ((size_t)(bh * 32 + kt)) * 4096 + row * 64 + (((d >> 3) ^ (row & 7)) << 3) + (d & 7);
}

// ---------------------------------------------------------------------------
// Kernel 1: convert fp32 inputs to fp16 (X split hi/lo; w_qkv rows permuted).
// ---------------------------------------------------------------------------
__global__ void split_inputs(const float* __restrict__ X, const float* __restrict__ Wq,
                             const float* __restrict__ Wf,
                             f16* __restrict__ Xh, f16* __restrict__ Xl,
                             f16* __restrict__ Wh, f16* __restrict__ Wfb) {
    const int tid = blockIdx.x * 256 + threadIdx.x;
    if (tid < 393216) {                       // X: 3,145,728 floats
        const float* s = X + (size_t)tid * 8;
        f16 hi[8], lo[8];
#pragma unroll
        for (int j = 0; j < 8; j += 4) {
            f32x4 v = *(const f32x4*)(s + j);
#pragma unroll
            for (int q = 0; q < 4; ++q) {
                f16 h = (f16)v[q];
                hi[j + q] = h;
                lo[j + q] = (f16)(v[q] - (float)h);
            }
        }
        *(f16x8*)(Xh + (size_t)tid * 8) = *(f16x8*)hi;
        *(f16x8*)(Xl + (size_t)tid * 8) = *(f16x8*)lo;
    } else if (tid < 614400) {                // w_qkv: row c*768+d*12+h -> c*768+h*64+d
        const int t2 = tid - 393216;
        const int row = t2 / 96;
        const int k = (t2 % 96) * 8;
        const int c = row / 768;
        const int rem = row - c * 768;
        const int d = rem / 12;
        const int h2 = rem - d * 12;
        const int cp = c * 768 + h2 * 64 + d;
        const float* s = Wq + (size_t)row * 768 + k;
        f16 hi[8];
#pragma unroll
        for (int j = 0; j < 8; j += 4) {
            f32x4 v = *(const f32x4*)(s + j);
#pragma unroll
            for (int q = 0; q < 4; ++q) hi[j + q] = (f16)v[q];
        }
        *(f16x8*)(Wh + (size_t)cp * 768 + k) = *(f16x8*)hi;
    } else {                                  // w_fc
        const int t2 = tid - 614400;
        const float* s = Wf + (size_t)t2 * 8;
        f16 hi[8];
#pragma unroll
        for (int j = 0; j < 8; j += 4) {
            f32x4 v = *(const f32x4*)(s + j);
#pragma unroll
            for (int q = 0; q < 4; ++q) hi[j + q] = (f16)v[q];
        }
        *(f16x8*)(Wfb + (size_t)t2 * 8) = *(f16x8*)hi;
    }
}

// ---------------------------------------------------------------------------
// Kernel 2: qkv GEMM (unchanged). fp16, Q/K cols 2 MFMA (x hi+lo), V 1.
// ---------------------------------------------------------------------------
__global__ __launch_bounds__(256) void qkv_gemm(
    const f16* __restrict__ Xh, const f16* __restrict__ Xl,
    const f16* __restrict__ Wh,
    f16* __restrict__ Qh, f16* __restrict__ Ql,
    f16* __restrict__ Khg, f16* __restrict__ Vb) {
    __shared__ f16 Ah[128 * 32], Al[128 * 32], Bh[128 * 32];
    const int t = threadIdx.x;
    const int lane = t & 63, wv = t >> 6;
    const int wm = (wv >> 1) * 64, wn = (wv & 1) * 64;
    const int r = lane & 15, g = lane >> 4;
    const int bm = blockIdx.x, bn = blockIdx.y;
    const bool full = (bn < 12);   // Q/K need the x-lo pass; V doesn't

    const int lrow = lane >> 2;
    const int lk = (lane & 3) * 8;

    f32x4 acc[4][4];
#pragma unroll
    for (int i = 0; i < 4; ++i)
#pragma unroll
        for (int j = 0; j < 4; ++j) acc[i][j] = (f32x4)0.0f;

    for (int ks = 0; ks < 768; ks += 32) {
#pragma unroll
        for (int hh = 0; hh < 2; ++hh) {
            const int ii = wv * 2 + hh;
            const int grow = ii * 16 + lrow;
            const size_t ga = (size_t)(bm * 128 + grow) * 768 + ks + lk;
            const size_t gb = (size_t)(bn * 128 + grow) * 768 + ks + lk;
            const int lbase = ii * 512;                  // wave-uniform LDS base
            gload_lds16(Xh + ga, &Ah[lbase]);
            gload_lds16(Wh + gb, &Bh[lbase]);
            if (full) gload_lds16(Xl + ga, &Al[lbase]);
        }
        __syncthreads();

        f16x8 a_h[4], b[4];
#pragma unroll
        for (int mf = 0; mf < 4; ++mf) a_h[mf] = *(f16x8*)&Ah[(wm + mf * 16 + r) * 32 + g * 8];
#pragma unroll
        for (int nf = 0; nf < 4; ++nf) b[nf] = *(f16x8*)&Bh[(wn + nf * 16 + r) * 32 + g * 8];
        if (full) {
            f16x8 a_l[4];
#pragma unroll
            for (int mf = 0; mf < 4; ++mf) a_l[mf] = *(f16x8*)&Al[(wm + mf * 16 + r) * 32 + g * 8];
#pragma unroll
            for (int mf = 0; mf < 4; ++mf)
#pragma unroll
                for (int nf = 0; nf < 4; ++nf) {
                    acc[mf][nf] = MFMA16(a_h[mf], b[nf], acc[mf][nf]);
                    acc[mf][nf] = MFMA16(a_l[mf], b[nf], acc[mf][nf]);
                }
        } else {
#pragma unroll
            for (int mf = 0; mf < 4; ++mf)
#pragma unroll
                for (int nf = 0; nf < 4; ++nf)
                    acc[mf][nf] = MFMA16(a_h[mf], b[nf], acc[mf][nf]);
        }
        __syncthreads();
    }

    const int comp = bn / 6;
#pragma unroll
    for (int mf = 0; mf < 4; ++mf)
#pragma unroll
        for (int nf = 0; nf < 4; ++nf) {
            const int col = bn * 128 + wn + nf * 16 + r;
            const int h = (col >> 6) % 12;
            const int d = col & 63;
#pragma unroll
            for (int v = 0; v < 4; ++v) {
                const int row = bm * 128 + wm + mf * 16 + g * 4 + v;
                const int b2 = row >> 11, n = row & 2047;
                const int bh = b2 * 12 + h;
                float val = acc[mf][nf][v];
                if (comp == 0) {
                    const size_t dest = ((size_t)bh * 2048 + n) * 64 + d;
                    val *= 8.0f;  // fold temperature (reference MULTIPLIES by sqrt(d_k))
                    f16 hi = (f16)val;
                    Qh[dest] = hi;
                    Ql[dest] = (f16)(val - (float)hi);
                } else if (comp == 1) {
                    Khg[kv_elem(bh, n, d)] = (f16)val;
                } else {
                    Vb[((size_t)bh * 2048 + n) * 64 + d] = (f16)val;
                }
            }
        }
}

// ---------------------------------------------------------------------------
// Kernel 2b: V transpose into the PERMUTED tiled image (R8 verbatim).
// Element (kv_local, d) at f16 index kc*2048 + d*32 + (g ^ ((d>>1)&3))*8 +
// u*4 + v  where kv_local = kc*32 + u*16 + g*4 + v.
// ---------------------------------------------------------------------------
__global__ void v_transpose(const f16* __restrict__ Vb, f16* __restrict__ VTg) {
    __shared__ f16 Vt[64 * 72];
    const int t = threadIdx.x;
    const int tile = blockIdx.x;              // bh*32 + kt
    const f16* src = Vb + (size_t)tile * 4096;
    const int row = t >> 2, d0 = (t & 3) * 16;
    *(f16x8*)&Vt[row * 72 + d0]     = *(const f16x8*)(src + row * 64 + d0);
    *(f16x8*)&Vt[row * 72 + d0 + 8] = *(const f16x8*)(src + row * 64 + d0 + 8);
    __syncthreads();
    f16* dst = VTg + (size_t)tile * 4096;
#pragma unroll
    for (int it = 0; it < 2; ++it) {
        const int c = t + it * 256;           // chunk id 0..511
        const int kc = c >> 8;
        const int d = (c >> 2) & 63;
        const int gg = c & 3;
        const int gl = gg ^ ((d >> 1) & 3);   // logical reader group g
        f16 o[8];
#pragma unroll
        for (int j = 0; j < 8; ++j) {
            const int kv = kc * 32 + (j >> 2) * 16 + gl * 4 + (j & 3);
            o[j] = Vt[kv * 72 + d];
        }
        *(f16x8*)(dst + (size_t)c * 8) = *(f16x8*)o;
    }
}

// ---------------------------------------------------------------------------
// Kernel 3: flash attention PARTIAL (KV-split x2). In-register P; TRANSPOSED
// PV (MFMA(V,P)) so lane owns row q=r: no rescale/norm shuffles, b64 O-writes.
// Block = 4 waves x 32 q rows; bid = (bh*2+half)*16 + qb (qb fastest for L2).
// grid 768, LDS 16 KB.
// ---------------------------------------------------------------------------
__global__ __launch_bounds__(256) void attn_partial(
    const f16* __restrict__ Qh, const f16* __restrict__ Ql,
    const f16* __restrict__ Khg, const f16* __restrict__ VTg,
    f16* __restrict__ OP, float* __restrict__ Mst, float* __restrict__ Lst) {
    __shared__ f16 Khs[4096], VTs[4096];

    const int t = threadIdx.x;
    const int lane = t & 63, wv = t >> 6;
    const int r = lane & 15, g = lane >> 4;
    const int bid = blockIdx.x;
    const int qb = bid & 15;
    const int half = (bid >> 4) & 1;
    const int bh = bid >> 5;          // 0..23
    const size_t headoff = (size_t)bh * 2048 * 64;
    const int q0w = qb * 128 + wv * 32;

    // Q fragments (B-operand): lane (r,g), qf: Q[q0w+qf*16+r][kc*32+g*8..+7]
    f16x8 qh[2][2], ql[2][2];
#pragma unroll
    for (int qf = 0; qf < 2; ++qf)
#pragma unroll
        for (int kc = 0; kc < 2; ++kc) {
            const size_t off = headoff + (size_t)(q0w + qf * 16 + r) * 64 + kc * 32 + g * 8;
            qh[qf][kc] = *(const f16x8*)(Qh + off);
            ql[qf][kc] = *(const f16x8*)(Ql + off);
        }

    // o_accT[qf][df]: O^T block — lane (r,g) reg v holds O[q0w+qf*16+r][df*16+g*4+v]
    f32x4 o_accT[2][4];
    float m_run[2] = {-1e30f, -1e30f}, l_run[2] = {0.0f, 0.0f};
#pragma unroll
    for (int qf = 0; qf < 2; ++qf)
#pragma unroll
        for (int df = 0; df < 4; ++df) o_accT[qf][df] = (f32x4)0.0f;

    for (int kt = half * 16; kt < half * 16 + 16; ++kt) {
        // ---- stage K and permuted-V^T images (8 KB each)
        const size_t tb = ((size_t)bh * 32 + kt) * 4096;
#pragma unroll
        for (int c2 = 0; c2 < 2; ++c2) {
            const int c = wv * 2 + c2;
            const int go = c * 512 + lane * 8;
            gload_lds16(Khg + tb + go, &Khs[c * 512]);
            gload_lds16(VTg + tb + go, &VTs[c * 512]);
        }
        __syncthreads();

        // ---- S^T = K Q^T : lane (r,g), qf gets S[q=r][k=cf*16+g*4+v]
        f32x4 s[2][4];
#pragma unroll
        for (int qf = 0; qf < 2; ++qf)
#pragma unroll
            for (int cf = 0; cf < 4; ++cf) s[qf][cf] = (f32x4)0.0f;
#pragma unroll
        for (int kc = 0; kc < 2; ++kc) {
            f16x8 ka[4];
#pragma unroll
            for (int cf = 0; cf < 4; ++cf)
                ka[cf] = *(f16x8*)&Khs[(cf * 16 + r) * 64 + (((kc * 4 + g) ^ (r & 7)) << 3)];
#pragma unroll
            for (int cf = 0; cf < 4; ++cf)
#pragma unroll
                for (int qf = 0; qf < 2; ++qf) {
                    s[qf][cf] = MFMA16(ka[cf], qh[qf][kc], s[qf][cf]);
                    s[qf][cf] = MFMA16(ka[cf], ql[qf][kc], s[qf][cf]);
                }
        }

        // ---- online softmax (lane owns row q0w+qf*16+r); P packed to regs
        f16x8 pa[2][2];
#pragma unroll
        for (int qf = 0; qf < 2; ++qf) {
            float mx = -1e30f;
#pragma unroll
            for (int cf = 0; cf < 4; ++cf)
#pragma unroll
                for (int v = 0; v < 4; ++v) mx = fmaxf(mx, s[qf][cf][v]);
            mx = fmaxf(mx, __shfl_xor(mx, 16));
            mx = fmaxf(mx, __shfl_xor(mx, 32));
            const float mn = fmaxf(m_run[qf], mx);
            const float sc = __expf(m_run[qf] - mn);
            m_run[qf] = mn;
            float rs = 0.0f;
#pragma unroll
            for (int cf = 0; cf < 4; ++cf)
#pragma unroll
                for (int v = 0; v < 4; ++v) {
                    const float p = __expf(s[qf][cf][v] - mn);
                    rs += p;
                    pa[qf][cf >> 1][(cf & 1) * 4 + v] = (f16)p;
                }
            rs += __shfl_xor(rs, 16);
            rs += __shfl_xor(rs, 32);
            l_run[qf] = l_run[qf] * sc + rs;
            // rescale O: lane owns its whole row -> plain vector scale, no shfl
#pragma unroll
            for (int df = 0; df < 4; ++df) o_accT[qf][df] *= sc;
        }

        // ---- O^T += V^T @ P^T (operand-swapped MFMA; same permuted V image)
#pragma unroll
        for (int kc = 0; kc < 2; ++kc)
#pragma unroll
            for (int df = 0; df < 4; ++df) {
                f16x8 vb = *(f16x8*)&VTs[kc * 2048 + (df * 16 + r) * 32 +
                                         ((g ^ ((r >> 1) & 3)) << 3)];
#pragma unroll
                for (int qf = 0; qf < 2; ++qf)
                    o_accT[qf][df] = MFMA16(vb, pa[qf][kc], o_accT[qf][df]);
            }
        __syncthreads();
    }

    // ---- write partial: unnormalized O (fp16, b64 per lane) + m,l stats
    const int pb = (bh << 1) + half;
#pragma unroll
    for (int qf = 0; qf < 2; ++qf) {
        const int n = q0w + qf * 16 + r;
        if (g == 0) {
            Mst[pb * 2048 + n] = m_run[qf];
            Lst[pb * 2048 + n] = l_run[qf];
        }
#pragma unroll
        for (int df = 0; df < 4; ++df) {
            f16 o4[4];
#pragma unroll
            for (int v = 0; v < 4; ++v) o4[v] = (f16)o_accT[qf][df][v];
            *(f16x4*)&OP[((size_t)pb * 2048 + n) * 64 + df * 16 + g * 4] = *(f16x4*)o4;
        }
    }
}

// ---------------------------------------------------------------------------
// Kernel 3b: combine the two KV-halves -> AO [b, n, h*64+d] fp16.
// 786432 threads (4 d-elems each), grid 3072. Fully coalesced.
// ---------------------------------------------------------------------------
__global__ void attn_combine(const f16* __restrict__ OP, const float* __restrict__ Mst,
                             const float* __restrict__ Lst, f16* __restrict__ AO) {
    const int tid = blockIdx.x * 256 + threadIdx.x;
    const int d4 = (tid & 15) * 4;
    const int pr = tid >> 4;          // bh*2048 + n
    const int bh = pr >> 11, n = pr & 2047;
    const int i1 = (bh * 2) * 2048 + n, i2 = i1 + 2048;
    const float m1 = Mst[i1], m2 = Mst[i2];
    const float l1 = Lst[i1], l2 = Lst[i2];
    const float m = fmaxf(m1, m2);
    const float w1 = __expf(m1 - m), w2 = __expf(m2 - m);
    const float inv = 1.0f / (w1 * l1 + w2 * l2);
    f16x4 o1 = *(const f16x4*)(OP + (size_t)i1 * 64 + d4);
    f16x4 o2 = *(const f16x4*)(OP + (size_t)i2 * 64 + d4);
    const int b = bh / 12, h = bh - b * 12;
    f16 out[4];
#pragma unroll
    for (int j = 0; j < 4; ++j)
        out[j] = (f16)((w1 * (float)o1[j] + w2 * (float)o2[j]) * inv);
    *(f16x4*)(AO + ((size_t)(b * 2048 + n)) * 768 + h * 64 + d4) = *(f16x4*)out;
}

// ---------------------------------------------------------------------------
// Kernel 4: out = AO @ Wfb^T + b_fc. 64x64 tiles, XOR-swizzled LDS,
// grid (64, 12) = 768 blocks. (unchanged)
// ---------------------------------------------------------------------------
__global__ __launch_bounds__(256) void fc_gemm(const f16* __restrict__ A,
                                               const f16* __restrict__ Wfb,
                                               const float* __restrict__ bias,
                                               float* __restrict__ OUT) {
    __shared__ f16 As[64 * 64], Bs[64 * 64];
    const int t = threadIdx.x;
    const int lane = t & 63, wv = t >> 6;
    const int wm = (wv >> 1) * 32, wn = (wv & 1) * 32;
    const int r = lane & 15, g = lane >> 4;
    const int bm = blockIdx.x, bn = blockIdx.y;

    f32x4 acc[2][2];
#pragma unroll
    for (int i = 0; i < 2; ++i)
#pragma unroll
        for (int j = 0; j < 2; ++j) acc[i][j] = (f32x4)0.0f;

    const int srow = t >> 2;
    const int ssg = (t & 3) * 2;

    for (int ks = 0; ks < 768; ks += 64) {
        const f16* as = A + (size_t)(bm * 64 + srow) * 768 + ks;
        const f16* bs = Wfb + (size_t)(bn * 64 + srow) * 768 + ks;
#pragma unroll
        for (int u = 0; u < 2; ++u) {
            const int sg = ssg + u;
            const int dst = srow * 64 + ((sg ^ (srow & 7)) << 3);
            *(f16x8*)&As[dst] = *(const f16x8*)(as + sg * 8);
            *(f16x8*)&Bs[dst] = *(const f16x8*)(bs + sg * 8);
        }
        __syncthreads();

#pragma unroll
        for (int kc = 0; kc < 2; ++kc) {
            f16x8 a[2], b[2];
#pragma unroll
            for (int mf = 0; mf < 2; ++mf) {
                const int row = wm + mf * 16 + r;
                a[mf] = *(f16x8*)&As[row * 64 + (((kc * 4 + g) ^ (row & 7)) << 3)];
            }
#pragma unroll
            for (int nf = 0; nf < 2; ++nf) {
                const int row = wn + nf * 16 + r;
                b[nf] = *(f16x8*)&Bs[row * 64 + (((kc * 4 + g) ^ (row & 7)) << 3)];
            }
#pragma unroll
            for (int mf = 0; mf < 2; ++mf)
#pragma unroll
                for (int nf = 0; nf < 2; ++nf)
                    acc[mf][nf] = MFMA16(a[mf], b[nf], acc[mf][nf]);
        }
        __syncthreads();
    }

#pragma unroll
    for (int nf = 0; nf < 2; ++nf) {
        const int col = bn * 64 + wn + nf * 16 + r;
        const float bv = bias[col];
#pragma unroll
        for (int mf = 0; mf < 2; ++mf) {
            const int row = bm * 64 + wm + mf * 16 + g * 4;
#pragma unroll
            for (int v = 0; v < 4; ++v)
                OUT[(size_t)(row + v) * 768 + col] = acc[mf][nf][v] + bv;
        }
    }
}

// ---------------------------------------------------------------------------
extern "C" void kernel_launch(void* const* d_in, const int* in_sizes, int n_in,
                              void* d_out, int out_size, void* d_ws, size_t ws_size,
                              hipStream_t stream) {
    (void)in_sizes; (void)n_in; (void)out_size; (void)ws_size;
    const float* x     = (const float*)d_in[0];   // [2,2048,768]
    const float* w_qkv = (const float*)d_in[1];   // [2304,768]
    const float* w_fc  = (const float*)d_in[2];   // [768,768]
    const float* b_fc  = (const float*)d_in[3];   // [768]
    float* out = (float*)d_out;                   // [2,2048,768] fp32

    char* ws = (char*)d_ws;
    f16* Xh  = (f16*)ws;                         // 3,145,728 f16 each (6 MB):
    f16* Xl  = Xh + 3145728;
    f16* Qh  = Xl + 3145728;
    f16* Ql  = Qh + 3145728;
    f16* Khg = Ql + 3145728;
    f16* Vb  = Khg + 3145728;
    f16* VTg = Vb + 3145728;
    f16* AO  = VTg + 3145728;
    f16* Wh  = AO + 3145728;                     // 1,769,472 f16
    f16* Wfb = Wh + 1769472;                     // 589,824 f16
    float* Mst = (float*)(Wfb + 589824);         // 98,304 floats (48 x 2048)
    float* Lst = Mst + 98304;
    f16* OP  = (f16*)(Lst + 98304);              // 6,291,456 f16 (FRESH, no alias)
    // total = 68,419,584 B

    split_inputs<<<2688, 256, 0, stream>>>(x, w_qkv, w_fc, Xh, Xl, Wh, Wfb);
    qkv_gemm<<<dim3(32, 18), 256, 0, stream>>>(Xh, Xl, Wh, Qh, Ql, Khg, Vb);
    v_transpose<<<768, 256, 0, stream>>>(Vb, VTg);
    attn_partial<<<768, 256, 0, stream>>>(Qh, Ql, Khg, VTg, OP, Mst, Lst);
    attn_combine<<<3072, 256, 0, stream>>>(OP, Mst, Lst, AO);
    fc_gemm<<<dim3(64, 12), 256, 0, stream>>>(AO, Wfb, b_fc, out);
}